// Round 10
// baseline (350.918 us; speedup 1.0000x reference)
//
#include <hip/hip_runtime.h>
#include <stdint.h>

using f32x4   = __attribute__((ext_vector_type(4))) float;
using short8  = __attribute__((ext_vector_type(8))) short;
using float4v = __attribute__((ext_vector_type(4))) float;
using float2v = __attribute__((ext_vector_type(2))) float;
using uint4v  = __attribute__((ext_vector_type(4))) unsigned int;

#define NCOL 11008
#define KDIM 4096
#define WSTRIDE 72    // LDS bytes per k-row: 32 cols * 2B + 8B pad (2-way reads)
#define BUFSZ (32 * WSTRIDE)   // 2304 B per (wave,buf)

__device__ __forceinline__ unsigned pk_bf16(float a, float b) {
  unsigned ua = __float_as_uint(a); ua += 0x7fffu + ((ua >> 16) & 1u);  // RNE
  unsigned ub = __float_as_uint(b); ub += 0x7fffu + ((ub >> 16) & 1u);
  return (ua >> 16) | (ub & 0xffff0000u);
}

// ---- kernel 1: mask (fp64-exact; verified green R5–R9) + write mask-zeroed
//      bf16 copy of x into ws. grid (8 rb, 8 kgrp), 256 thr.
__global__ __launch_bounds__(256) void mask_convert_kernel(
    const float* __restrict__ x, unsigned* __restrict__ xbf) {
  const int rb = blockIdx.x;
  const int g  = blockIdx.y;
  const int t  = threadIdx.x;
  __shared__ double part[256];
  __shared__ unsigned sh_bits;

  const float* base = x + (size_t)rb * 16 * KDIM + g * 512 + t * 2;
  double s = 0.0;
#pragma unroll
  for (int r = 0; r < 16; ++r) {
    float2v a = *(const float2v*)(base + (size_t)r * KDIM);
    s += (double)fabsf(a[0]) + (double)fabsf(a[1]);
  }
  part[t] = s;
  __syncthreads();
  if (t < 8) {                        // t = kb-local (8 kbs per 512-col group)
    double acc = 0.0;
#pragma unroll
    for (int u = 0; u < 32; ++u) acc += part[t * 32 + u];
    bool on = (acc * (1.0 / 1024.0)) > (double)0.8f;
    unsigned long long bal = __ballot(on);
    if (t == 0) sh_bits = (unsigned)(bal & 0xffu);
  }
  __syncthreads();
  const unsigned keep = (sh_bits >> (t >> 5)) & 1u;

  unsigned* dst = xbf + (size_t)rb * 16 * (KDIM / 2) + g * 256 + t;
#pragma unroll
  for (int r = 0; r < 16; ++r) {      // reload (L1-hot) + pack/zero + store
    float2v a = *(const float2v*)(base + (size_t)r * KDIM);
    dst[(size_t)r * (KDIM / 2)] = keep ? pk_bf16(a[0], a[1]) : 0u;
  }
}

// ---- kernel 2: dense GEMM on masked bf16 x. grid 344, block 128 (2 waves).
// M=128 x N=32 per block, K split across the 2 waves (wave wv owns
// k in [kb*64+wv*32, +32) for every kb) -> NO in-loop barriers: each wave
// stages its private 32x32 W strip (fp32->bf16) into its own LDS dbuf,
// accumulates partials, merges once at the epilogue (2 barriers total).
// Every W byte is requested by exactly one wave chip-wide; no atomics.
__global__ __launch_bounds__(128) void gemm_kernel(
    const unsigned* __restrict__ xbf, const float* __restrict__ w,
    const float* __restrict__ bias, float* __restrict__ out) {

  __shared__ __align__(16) uint8_t lds[16384];   // 4x2304 staging; epilogue 16K

  const int tid  = threadIdx.x;
  const int lane = tid & 63;
  const int wv   = tid >> 6;          // k-half owner
  const int c    = lane & 15;
  const int q    = lane >> 4;
  const int n0   = blockIdx.x * 32;

  uint8_t* myLds = lds + wv * 2 * BUFSZ;

  f32x4 acc[8][2] = {};               // [m-tile][even/odd col frag]

  // W staging: lane covers row r=lane>>1 (of this wave's 32), col-half h=lane&1
  // -> lane pair consumes one full 128B line; 64B contiguous per lane.
  const int sr = lane >> 1, sh = lane & 1;
  const float* wBase = w + (size_t)(wv * 32 + sr) * NCOL + n0 + sh * 16;
  const int ldsOff = sr * WSTRIDE + sh * 32;

  float4v wr[2][4];                   // depth-2 register prefetch
#define ISSUE_W(KB)                                                     \
  {                                                                     \
    const float* wp = wBase + (size_t)(KB) * 64 * NCOL;                 \
    wr[(KB) & 1][0] = *(const float4v*)(wp);                            \
    wr[(KB) & 1][1] = *(const float4v*)(wp + 4);                        \
    wr[(KB) & 1][2] = *(const float4v*)(wp + 8);                        \
    wr[(KB) & 1][3] = *(const float4v*)(wp + 12);                       \
  }

  // A source (bf16 masked x, L2-resident):
  // uint4 idx = (mt*16+c)*512 + kb*8 + wv*4 + q  ->  k = kb*64+wv*32+q*8+..7
  const uint4v* aBase = (const uint4v*)xbf + (size_t)c * 512 + wv * 4 + q;

  ISSUE_W(0);
  ISSUE_W(1);
  for (int kb = 0; kb < 64; ++kb) {
    const int b = kb & 1;
    uint8_t* buf = myLds + b * BUFSZ;

    // pack current kb's W (fine-grained vmcnt wait on wr[b] only) -> LDS
    uint4v v0, v1;
    v0[0] = pk_bf16(wr[b][0][0], wr[b][0][1]);
    v0[1] = pk_bf16(wr[b][0][2], wr[b][0][3]);
    v0[2] = pk_bf16(wr[b][1][0], wr[b][1][1]);
    v0[3] = pk_bf16(wr[b][1][2], wr[b][1][3]);
    v1[0] = pk_bf16(wr[b][2][0], wr[b][2][1]);
    v1[1] = pk_bf16(wr[b][2][2], wr[b][2][3]);
    v1[2] = pk_bf16(wr[b][3][0], wr[b][3][1]);
    v1[3] = pk_bf16(wr[b][3][2], wr[b][3][3]);
    *(uint4v*)(buf + ldsOff) = v0;
    *(uint4v*)(buf + ldsOff + 16) = v1;

    if (kb < 62) ISSUE_W(kb + 2);     // refill wr[b]; stays in flight freely

    // A fragments for all 8 m-tiles (L2 reads overlap the LDS round-trip)
    union { uint4v u; short8 v; } am[8];
#pragma unroll
    for (int mt = 0; mt < 8; ++mt)
      am[mt].u = aBase[(size_t)mt * 16 * 512 + kb * 8];

    // B fragments: dword j = cols (2c,2c+1) at local k = q*8+j (2-way, free)
    const uint8_t* wb = buf + (size_t)q * 8 * WSTRIDE + c * 4;
    unsigned wj[8];
#pragma unroll
    for (int j = 0; j < 8; ++j)
      wj[j] = *(const unsigned*)(wb + (size_t)j * WSTRIDE);
    union { short8 v; unsigned u[4]; } be, bo;
#pragma unroll
    for (int p = 0; p < 4; ++p) {
      be.u[p] = (wj[2 * p] & 0x0000ffffu) | (wj[2 * p + 1] << 16);   // even col
      bo.u[p] = (wj[2 * p] >> 16) | (wj[2 * p + 1] & 0xffff0000u);   // odd col
    }
#pragma unroll
    for (int mt = 0; mt < 8; ++mt) {
      acc[mt][0] = __builtin_amdgcn_mfma_f32_16x16x32_bf16(am[mt].v, be.v, acc[mt][0], 0, 0, 0);
      acc[mt][1] = __builtin_amdgcn_mfma_f32_16x16x32_bf16(am[mt].v, bo.v, acc[mt][1], 0, 0, 0);
    }
  }
#undef ISSUE_W

  // ---- epilogue: merge the two waves' k-partials via LDS (2 barriers) ----
  __syncthreads();                    // staging bufs dead; LDS reused
  if (wv == 0) {
#pragma unroll
    for (int mt = 0; mt < 8; ++mt)
#pragma unroll
      for (int eo = 0; eo < 2; ++eo)
        *(f32x4*)(lds + ((size_t)(mt * 2 + eo) * 64 + lane) * 16) = acc[mt][eo];
  }
  __syncthreads();
  if (wv == 1) {
    const int colE = n0 + 2 * c;
    const float bE = bias[colE];
    const float bO = bias[colE + 1];
#pragma unroll
    for (int mt = 0; mt < 8; ++mt) {
      f32x4 pe = *(const f32x4*)(lds + ((size_t)(mt * 2 + 0) * 64 + lane) * 16);
      f32x4 po = *(const f32x4*)(lds + ((size_t)(mt * 2 + 1) * 64 + lane) * 16);
#pragma unroll
      for (int p = 0; p < 4; ++p) {
        const int row = mt * 16 + q * 4 + p;
        float2v st;
        st[0] = acc[mt][0][p] + pe[p] + bE;
        st[1] = acc[mt][1][p] + po[p] + bO;
        *(float2v*)(out + (size_t)row * NCOL + colE) = st;   // 8B-aligned
      }
    }
  }
}

extern "C" void kernel_launch(void* const* d_in, const int* in_sizes, int n_in,
                              void* d_out, int out_size, void* d_ws, size_t ws_size,
                              hipStream_t stream) {
  const float* x    = (const float*)d_in[0];
  const float* w    = (const float*)d_in[1];
  const float* bias = (const float*)d_in[2];
  float* out        = (float*)d_out;
  unsigned* xbf     = (unsigned*)d_ws;    // 128 x 4096 bf16 (1 MiB)

  hipLaunchKernelGGL(mask_convert_kernel, dim3(8, 8), dim3(256), 0, stream, x, xbf);
  hipLaunchKernelGGL(gemm_kernel, dim3(344), dim3(128), 0, stream,
                     xbf, w, bias, out);
}

// Round 11
// 346.762 us; speedup vs baseline: 1.0120x; 1.0120x over previous
//
#include <hip/hip_runtime.h>
#include <stdint.h>

using f32x4   = __attribute__((ext_vector_type(4))) float;
using short8  = __attribute__((ext_vector_type(8))) short;
using float4v = __attribute__((ext_vector_type(4))) float;
using float2v = __attribute__((ext_vector_type(2))) float;
using uint4v  = __attribute__((ext_vector_type(4))) unsigned int;

#define NCOL 11008
#define KDIM 4096
#define WSTRIDE 72          // LDS bytes per k-row: 32 cols * 2B + 8B pad
#define KBUF (64 * WSTRIDE) // 4608 B per kb buffer

__device__ __forceinline__ unsigned pk_bf16(float a, float b) {
  unsigned ua = __float_as_uint(a); ua += 0x7fffu + ((ua >> 16) & 1u);  // RNE
  unsigned ub = __float_as_uint(b); ub += 0x7fffu + ((ub >> 16) & 1u);
  return (ua >> 16) | (ub & 0xffff0000u);
}

// ---- kernel 1: mask (fp64-exact; verified green R5–R10) + write mask-zeroed
//      bf16 copy of x into ws. grid (8 rb, 8 kgrp), 256 thr.
__global__ __launch_bounds__(256) void mask_convert_kernel(
    const float* __restrict__ x, unsigned* __restrict__ xbf) {
  const int rb = blockIdx.x;
  const int g  = blockIdx.y;
  const int t  = threadIdx.x;
  __shared__ double part[256];
  __shared__ unsigned sh_bits;

  const float* base = x + (size_t)rb * 16 * KDIM + g * 512 + t * 2;
  double s = 0.0;
#pragma unroll
  for (int r = 0; r < 16; ++r) {
    float2v a = *(const float2v*)(base + (size_t)r * KDIM);
    s += (double)fabsf(a[0]) + (double)fabsf(a[1]);
  }
  part[t] = s;
  __syncthreads();
  if (t < 8) {                        // t = kb-local (8 kbs per 512-col group)
    double acc = 0.0;
#pragma unroll
    for (int u = 0; u < 32; ++u) acc += part[t * 32 + u];
    bool on = (acc * (1.0 / 1024.0)) > (double)0.8f;
    unsigned long long bal = __ballot(on);
    if (t == 0) sh_bits = (unsigned)(bal & 0xffu);
  }
  __syncthreads();
  const unsigned keep = (sh_bits >> (t >> 5)) & 1u;

  unsigned* dst = xbf + (size_t)rb * 16 * (KDIM / 2) + g * 256 + t;
#pragma unroll
  for (int r = 0; r < 16; ++r) {      // reload (L1-hot) + pack/zero + store
    float2v a = *(const float2v*)(base + (size_t)r * KDIM);
    dst[(size_t)r * (KDIM / 2)] = keep ? pk_bf16(a[0], a[1]) : 0u;
  }
}

// ---- kernel 2: dense GEMM on masked bf16 x. grid (344 n-tiles, 4 kz),
// block = 64 (ONE wave). M=128 x N=32 x K-quarter(1024) per block; partial
// sums to ws; no barriers, no atomics; every W byte read by exactly one
// wave chip-wide. Depth-2 W register prefetch; per-kb issue order keeps all
// vmcnt waits fine-grained (A first, then pack old W, then issue W+2).
__global__ __launch_bounds__(64) void gemm_kernel(
    const unsigned* __restrict__ xbf, const float* __restrict__ w,
    float* __restrict__ pws) {

  __shared__ __align__(16) uint8_t lds[2 * KBUF];

  const int lane = threadIdx.x;       // 0..63
  const int c    = lane & 15;
  const int q    = lane >> 4;
  const int n0   = blockIdx.x * 32;
  const int kz   = blockIdx.y;        // K-quarter

  f32x4 acc[8][2] = {};               // [m-tile][even/odd col frag]

  // W staging: 4 lanes per k-row line; lane covers row rr=lane>>2 (+16m),
  // cols (lane&3)*8 .. +7 (32B fp32 = 2 float4, contiguous per lane).
  const int rr = lane >> 2, q4 = lane & 3;
  const float* wBase = w + (size_t)(kz * 1024 + rr) * NCOL + n0 + q4 * 8;
  const int ldsWOff = rr * WSTRIDE + q4 * 16;

  float4v wr[2][8];                   // depth-2 prefetch: [kb&1][m*2+h]
#define ISSUE_W(KBL)                                                    \
  {                                                                     \
    const float* wp = wBase + (size_t)(KBL) * 64 * NCOL;                \
    _Pragma("unroll")                                                   \
    for (int m = 0; m < 4; ++m) {                                       \
      wr[(KBL) & 1][m * 2 + 0] = *(const float4v*)(wp + (size_t)m * 16 * NCOL);     \
      wr[(KBL) & 1][m * 2 + 1] = *(const float4v*)(wp + (size_t)m * 16 * NCOL + 4); \
    }                                                                   \
  }

  // A source (bf16 masked x, L2-resident): uint4 idx =
  //   (mt*16 + c)*512 + kz*128 + kbl*8 + ks*4 + q
  const uint4v* aBase = (const uint4v*)xbf + (size_t)c * 512 + kz * 128 + q;

  ISSUE_W(0);
  ISSUE_W(1);
  for (int kbl = 0; kbl < 16; ++kbl) {
    const int b = kbl & 1;
    uint8_t* buf = lds + b * KBUF;

    // (1) A loads FIRST — issued before next-W so consuming them never
    //     drains the W prefetch queue (vmcnt is in-order).
    union { uint4v u; short8 v; } am[2][8];
#pragma unroll
    for (int ks = 0; ks < 2; ++ks)
#pragma unroll
      for (int mt = 0; mt < 8; ++mt)
        am[ks][mt].u = aBase[(size_t)mt * 16 * 512 + kbl * 8 + ks * 4];

    // (2) pack current kb's W (waits only the OLD wr[b] loads) -> LDS
#pragma unroll
    for (int m = 0; m < 4; ++m) {
      uint4v v;
      v[0] = pk_bf16(wr[b][m * 2 + 0][0], wr[b][m * 2 + 0][1]);
      v[1] = pk_bf16(wr[b][m * 2 + 0][2], wr[b][m * 2 + 0][3]);
      v[2] = pk_bf16(wr[b][m * 2 + 1][0], wr[b][m * 2 + 1][1]);
      v[3] = pk_bf16(wr[b][m * 2 + 1][2], wr[b][m * 2 + 1][3]);
      *(uint4v*)(buf + (size_t)m * 16 * WSTRIDE + ldsWOff) = v;
    }

    // (3) refill wr[b] two kbs ahead — stays in flight across iterations
    if (kbl < 14) ISSUE_W(kbl + 2);

    // (4) compute (ds_read waits lgkmcnt only; MFMA's A-wait leaves the
    //     8 W(kbl+2) loads outstanding)
#pragma unroll
    for (int ks = 0; ks < 2; ++ks) {
      const uint8_t* wb = buf + (size_t)(ks * 32 + q * 8) * WSTRIDE + c * 4;
      unsigned wj[8];
#pragma unroll
      for (int j = 0; j < 8; ++j)
        wj[j] = *(const unsigned*)(wb + (size_t)j * WSTRIDE);
      union { short8 v; unsigned u[4]; } be, bo;
#pragma unroll
      for (int p = 0; p < 4; ++p) {
        be.u[p] = (wj[2 * p] & 0x0000ffffu) | (wj[2 * p + 1] << 16);   // even col
        bo.u[p] = (wj[2 * p] >> 16) | (wj[2 * p + 1] & 0xffff0000u);   // odd col
      }
#pragma unroll
      for (int mt = 0; mt < 8; ++mt) {
        acc[mt][0] = __builtin_amdgcn_mfma_f32_16x16x32_bf16(am[ks][mt].v, be.v, acc[mt][0], 0, 0, 0);
        acc[mt][1] = __builtin_amdgcn_mfma_f32_16x16x32_bf16(am[ks][mt].v, bo.v, acc[mt][1], 0, 0, 0);
      }
    }
  }
#undef ISSUE_W

  // epilogue: partial tile [128][32] fp32 to ws at [ntile][kz]
  float* P = pws + ((size_t)blockIdx.x * 4 + kz) * (128 * 32);
#pragma unroll
  for (int mt = 0; mt < 8; ++mt) {
#pragma unroll
    for (int p = 0; p < 4; ++p) {
      const int row = mt * 16 + q * 4 + p;
      float2v st;
      st[0] = acc[mt][0][p];
      st[1] = acc[mt][1][p];
      *(float2v*)(P + (size_t)row * 32 + 2 * c) = st;   // q-group = full 128B line
    }
  }
}

// ---- kernel 3: reduce 4 kz-partials + bias -> out. grid 2752 x 256.
__global__ __launch_bounds__(256) void reduce_kernel(
    const float* __restrict__ pws, const float* __restrict__ bias,
    float* __restrict__ out) {
  const int idx = blockIdx.x * 256 + threadIdx.x;   // 704512 float2's
  const int c2  = idx & 15;
  const int r   = (idx >> 4) & 127;
  const int nt  = idx >> 11;
  const float* p = pws + (size_t)nt * 4 * (128 * 32) + (size_t)r * 32 + c2 * 2;
  float2v s0 = *(const float2v*)(p);
  float2v s1 = *(const float2v*)(p + 128 * 32);
  float2v s2 = *(const float2v*)(p + 2 * 128 * 32);
  float2v s3 = *(const float2v*)(p + 3 * 128 * 32);
  const int col = nt * 32 + c2 * 2;
  float2v o;
  o[0] = s0[0] + s1[0] + s2[0] + s3[0] + bias[col];
  o[1] = s0[1] + s1[1] + s2[1] + s3[1] + bias[col + 1];
  *(float2v*)(out + (size_t)r * NCOL + col) = o;
}

extern "C" void kernel_launch(void* const* d_in, const int* in_sizes, int n_in,
                              void* d_out, int out_size, void* d_ws, size_t ws_size,
                              hipStream_t stream) {
  const float* x    = (const float*)d_in[0];
  const float* w    = (const float*)d_in[1];
  const float* bias = (const float*)d_in[2];
  float* out        = (float*)d_out;
  unsigned* xbf     = (unsigned*)d_ws;                       // 1 MiB bf16 x
  float* pws        = (float*)((char*)d_ws + (1u << 20));    // 22.5 MiB partials

  hipLaunchKernelGGL(mask_convert_kernel, dim3(8, 8), dim3(256), 0, stream, x, xbf);
  hipLaunchKernelGGL(gemm_kernel, dim3(344, 4), dim3(64), 0, stream, xbf, w, pws);
  hipLaunchKernelGGL(reduce_kernel, dim3(2752), dim3(256), 0, stream, pws, bias, out);
}

// Round 12
// 346.580 us; speedup vs baseline: 1.0125x; 1.0005x over previous
//
#include <hip/hip_runtime.h>
#include <stdint.h>

using f32x4   = __attribute__((ext_vector_type(4))) float;
using short8  = __attribute__((ext_vector_type(8))) short;
using float4v = __attribute__((ext_vector_type(4))) float;
using float2v = __attribute__((ext_vector_type(2))) float;
using uint4v  = __attribute__((ext_vector_type(4))) unsigned int;

#define NCOL 11008
#define KDIM 4096
#define WSTRIDE 72          // LDS bytes per k-row: 32 cols * 2B + 8B pad
#define KBUF (64 * WSTRIDE) // 4608 B per kb buffer

__device__ __forceinline__ unsigned pk_bf16(float a, float b) {
  unsigned ua = __float_as_uint(a); ua += 0x7fffu + ((ua >> 16) & 1u);  // RNE
  unsigned ub = __float_as_uint(b); ub += 0x7fffu + ((ub >> 16) & 1u);
  return (ua >> 16) | (ub & 0xffff0000u);
}

// ---- kernel 1: mask (fp64-exact; verified green R5–R11) + write mask-zeroed
//      bf16 copy of x into ws. grid (8 rb, 8 kgrp), 256 thr.
__global__ __launch_bounds__(256) void mask_convert_kernel(
    const float* __restrict__ x, unsigned* __restrict__ xbf) {
  const int rb = blockIdx.x;
  const int g  = blockIdx.y;
  const int t  = threadIdx.x;
  __shared__ double part[256];
  __shared__ unsigned sh_bits;

  const float* base = x + (size_t)rb * 16 * KDIM + g * 512 + t * 2;
  double s = 0.0;
#pragma unroll
  for (int r = 0; r < 16; ++r) {
    float2v a = *(const float2v*)(base + (size_t)r * KDIM);
    s += (double)fabsf(a[0]) + (double)fabsf(a[1]);
  }
  part[t] = s;
  __syncthreads();
  if (t < 8) {                        // t = kb-local (8 kbs per 512-col group)
    double acc = 0.0;
#pragma unroll
    for (int u = 0; u < 32; ++u) acc += part[t * 32 + u];
    bool on = (acc * (1.0 / 1024.0)) > (double)0.8f;
    unsigned long long bal = __ballot(on);
    if (t == 0) sh_bits = (unsigned)(bal & 0xffu);
  }
  __syncthreads();
  const unsigned keep = (sh_bits >> (t >> 5)) & 1u;

  unsigned* dst = xbf + (size_t)rb * 16 * (KDIM / 2) + g * 256 + t;
#pragma unroll
  for (int r = 0; r < 16; ++r) {      // reload (L1-hot) + pack/zero + store
    float2v a = *(const float2v*)(base + (size_t)r * KDIM);
    dst[(size_t)r * (KDIM / 2)] = keep ? pk_bf16(a[0], a[1]) : 0u;
  }
}

// ---- kernel 2: dense GEMM on masked bf16 x. grid (344 n-tiles, 4 kz),
// block = 64 (ONE wave). M=128 x N=32 x K-quarter(1024) per block; partial
// sums to ws; no barriers, no atomics; every W byte read by exactly one
// wave chip-wide. Depth-2 W register prefetch; per-kb issue order keeps all
// vmcnt waits fine-grained (A first, then pack old W, then issue W+2).
// __launch_bounds__(64, 1): R11's compiler default capped VGPRs at 88 and
// spilled wr/am to scratch (195 MB WRITE) — min-waves=1 lifts the cap.
__global__ __launch_bounds__(64, 1) void gemm_kernel(
    const unsigned* __restrict__ xbf, const float* __restrict__ w,
    float* __restrict__ pws) {

  __shared__ __align__(16) uint8_t lds[2 * KBUF];

  const int lane = threadIdx.x;       // 0..63
  const int c    = lane & 15;
  const int q    = lane >> 4;
  const int n0   = blockIdx.x * 32;
  const int kz   = blockIdx.y;        // K-quarter

  f32x4 acc[8][2] = {};               // [m-tile][even/odd col frag]

  // W staging: 4 lanes per k-row line; lane covers row rr=lane>>2 (+16m),
  // cols (lane&3)*8 .. +7 (32B fp32 = 2 float4, contiguous per lane).
  const int rr = lane >> 2, q4 = lane & 3;
  const float* wBase = w + (size_t)(kz * 1024 + rr) * NCOL + n0 + q4 * 8;
  const int ldsWOff = rr * WSTRIDE + q4 * 16;

  float4v wr[2][8];                   // depth-2 prefetch: [kb&1][m*2+h]
#define ISSUE_W(KBL)                                                    \
  {                                                                     \
    const float* wp = wBase + (size_t)(KBL) * 64 * NCOL;                \
    _Pragma("unroll")                                                   \
    for (int m = 0; m < 4; ++m) {                                       \
      wr[(KBL) & 1][m * 2 + 0] = *(const float4v*)(wp + (size_t)m * 16 * NCOL);     \
      wr[(KBL) & 1][m * 2 + 1] = *(const float4v*)(wp + (size_t)m * 16 * NCOL + 4); \
    }                                                                   \
  }

  // A source (bf16 masked x, L2-resident): uint4 idx =
  //   (mt*16 + c)*512 + kz*128 + kbl*8 + ks*4 + q
  const uint4v* aBase = (const uint4v*)xbf + (size_t)c * 512 + kz * 128 + q;

  ISSUE_W(0);
  ISSUE_W(1);
  for (int kbl = 0; kbl < 16; ++kbl) {
    const int b = kbl & 1;
    uint8_t* buf = lds + b * KBUF;

    // (1) A loads FIRST — issued before next-W so consuming them never
    //     drains the W prefetch queue (vmcnt is in-order).
    union { uint4v u; short8 v; } am[2][8];
#pragma unroll
    for (int ks = 0; ks < 2; ++ks)
#pragma unroll
      for (int mt = 0; mt < 8; ++mt)
        am[ks][mt].u = aBase[(size_t)mt * 16 * 512 + kbl * 8 + ks * 4];

    // (2) pack current kb's W (waits only the OLD wr[b] loads) -> LDS
#pragma unroll
    for (int m = 0; m < 4; ++m) {
      uint4v v;
      v[0] = pk_bf16(wr[b][m * 2 + 0][0], wr[b][m * 2 + 0][1]);
      v[1] = pk_bf16(wr[b][m * 2 + 0][2], wr[b][m * 2 + 0][3]);
      v[2] = pk_bf16(wr[b][m * 2 + 1][0], wr[b][m * 2 + 1][1]);
      v[3] = pk_bf16(wr[b][m * 2 + 1][2], wr[b][m * 2 + 1][3]);
      *(uint4v*)(buf + (size_t)m * 16 * WSTRIDE + ldsWOff) = v;
    }

    // (3) refill wr[b] two kbs ahead — stays in flight across iterations
    if (kbl < 14) ISSUE_W(kbl + 2);

    // (4) compute (ds_read waits lgkmcnt only; MFMA's A-wait leaves the
    //     8 W(kbl+2) loads outstanding)
#pragma unroll
    for (int ks = 0; ks < 2; ++ks) {
      const uint8_t* wb = buf + (size_t)(ks * 32 + q * 8) * WSTRIDE + c * 4;
      unsigned wj[8];
#pragma unroll
      for (int j = 0; j < 8; ++j)
        wj[j] = *(const unsigned*)(wb + (size_t)j * WSTRIDE);
      union { short8 v; unsigned u[4]; } be, bo;
#pragma unroll
      for (int p = 0; p < 4; ++p) {
        be.u[p] = (wj[2 * p] & 0x0000ffffu) | (wj[2 * p + 1] << 16);   // even col
        bo.u[p] = (wj[2 * p] >> 16) | (wj[2 * p + 1] & 0xffff0000u);   // odd col
      }
#pragma unroll
      for (int mt = 0; mt < 8; ++mt) {
        acc[mt][0] = __builtin_amdgcn_mfma_f32_16x16x32_bf16(am[ks][mt].v, be.v, acc[mt][0], 0, 0, 0);
        acc[mt][1] = __builtin_amdgcn_mfma_f32_16x16x32_bf16(am[ks][mt].v, bo.v, acc[mt][1], 0, 0, 0);
      }
    }
  }
#undef ISSUE_W

  // epilogue: partial tile [128][32] fp32 to ws at [ntile][kz]
  float* P = pws + ((size_t)blockIdx.x * 4 + kz) * (128 * 32);
#pragma unroll
  for (int mt = 0; mt < 8; ++mt) {
#pragma unroll
    for (int p = 0; p < 4; ++p) {
      const int row = mt * 16 + q * 4 + p;
      float2v st;
      st[0] = acc[mt][0][p];
      st[1] = acc[mt][1][p];
      *(float2v*)(P + (size_t)row * 32 + 2 * c) = st;   // q-group = full 128B line
    }
  }
}

// ---- kernel 3: reduce 4 kz-partials + bias -> out. grid 2752 x 256.
__global__ __launch_bounds__(256) void reduce_kernel(
    const float* __restrict__ pws, const float* __restrict__ bias,
    float* __restrict__ out) {
  const int idx = blockIdx.x * 256 + threadIdx.x;   // 704512 float2's
  const int c2  = idx & 15;
  const int r   = (idx >> 4) & 127;
  const int nt  = idx >> 11;
  const float* p = pws + (size_t)nt * 4 * (128 * 32) + (size_t)r * 32 + c2 * 2;
  float2v s0 = *(const float2v*)(p);
  float2v s1 = *(const float2v*)(p + 128 * 32);
  float2v s2 = *(const float2v*)(p + 2 * 128 * 32);
  float2v s3 = *(const float2v*)(p + 3 * 128 * 32);
  const int col = nt * 32 + c2 * 2;
  float2v o;
  o[0] = s0[0] + s1[0] + s2[0] + s3[0] + bias[col];
  o[1] = s0[1] + s1[1] + s2[1] + s3[1] + bias[col + 1];
  *(float2v*)(out + (size_t)r * NCOL + col) = o;
}

extern "C" void kernel_launch(void* const* d_in, const int* in_sizes, int n_in,
                              void* d_out, int out_size, void* d_ws, size_t ws_size,
                              hipStream_t stream) {
  const float* x    = (const float*)d_in[0];
  const float* w    = (const float*)d_in[1];
  const float* bias = (const float*)d_in[2];
  float* out        = (float*)d_out;
  unsigned* xbf     = (unsigned*)d_ws;                       // 1 MiB bf16 x
  float* pws        = (float*)((char*)d_ws + (1u << 20));    // 22.5 MiB partials

  hipLaunchKernelGGL(mask_convert_kernel, dim3(8, 8), dim3(256), 0, stream, x, xbf);
  hipLaunchKernelGGL(gemm_kernel, dim3(344, 4), dim3(64), 0, stream, xbf, w, pws);
  hipLaunchKernelGGL(reduce_kernel, dim3(2752), dim3(256), 0, stream, pws, bias, out);
}

// Round 13
// 297.732 us; speedup vs baseline: 1.1786x; 1.1641x over previous
//
#include <hip/hip_runtime.h>
#include <stdint.h>

using f32x4   = __attribute__((ext_vector_type(4))) float;
using short8  = __attribute__((ext_vector_type(8))) short;
using float4v = __attribute__((ext_vector_type(4))) float;
using float2v = __attribute__((ext_vector_type(2))) float;
using uint4v  = __attribute__((ext_vector_type(4))) unsigned int;

#define NCOL 11008
#define KDIM 4096
#define WSTRIDE 72          // LDS bytes per k-row: 32 cols * 2B + 8B pad
#define KBUF (64 * WSTRIDE) // 4608 B per kb buffer

__device__ __forceinline__ unsigned pk_bf16(float a, float b) {
  unsigned ua = __float_as_uint(a); ua += 0x7fffu + ((ua >> 16) & 1u);  // RNE
  unsigned ub = __float_as_uint(b); ub += 0x7fffu + ((ub >> 16) & 1u);
  return (ua >> 16) | (ub & 0xffff0000u);
}

// ---- kernel 1: mask (fp64-exact; verified green R5–R12) + write mask-zeroed
//      bf16 copy of x into ws. grid (8 rb, 8 kgrp), 256 thr.
__global__ __launch_bounds__(256) void mask_convert_kernel(
    const float* __restrict__ x, unsigned* __restrict__ xbf) {
  const int rb = blockIdx.x;
  const int g  = blockIdx.y;
  const int t  = threadIdx.x;
  __shared__ double part[256];
  __shared__ unsigned sh_bits;

  const float* base = x + (size_t)rb * 16 * KDIM + g * 512 + t * 2;
  double s = 0.0;
#pragma unroll
  for (int r = 0; r < 16; ++r) {
    float2v a = *(const float2v*)(base + (size_t)r * KDIM);
    s += (double)fabsf(a[0]) + (double)fabsf(a[1]);
  }
  part[t] = s;
  __syncthreads();
  if (t < 8) {                        // t = kb-local (8 kbs per 512-col group)
    double acc = 0.0;
#pragma unroll
    for (int u = 0; u < 32; ++u) acc += part[t * 32 + u];
    bool on = (acc * (1.0 / 1024.0)) > (double)0.8f;
    unsigned long long bal = __ballot(on);
    if (t == 0) sh_bits = (unsigned)(bal & 0xffu);
  }
  __syncthreads();
  const unsigned keep = (sh_bits >> (t >> 5)) & 1u;

  unsigned* dst = xbf + (size_t)rb * 16 * (KDIM / 2) + g * 256 + t;
#pragma unroll
  for (int r = 0; r < 16; ++r) {      // reload (L1-hot) + pack/zero + store
    float2v a = *(const float2v*)(base + (size_t)r * KDIM);
    dst[(size_t)r * (KDIM / 2)] = keep ? pk_bf16(a[0], a[1]) : 0u;
  }
}

// ---- kernel 2: dense GEMM on masked bf16 x. grid (344 n-tiles, 4 kz),
// block = 64 (ONE wave). M=128 x N=32 x K-quarter(1024); partials to ws; no
// barriers/atomics; every W byte read once chip-wide. Depth-2 W prefetch in
// two STATICALLY-NAMED register sets wrA/wrB (R11/R12's wr[(kb)&1] runtime
// index forced the array to scratch -> 195 MB spill traffic; all indices
// must be compile-time for registers).
__global__ __launch_bounds__(64, 1) void gemm_kernel(
    const unsigned* __restrict__ xbf, const float* __restrict__ w,
    float* __restrict__ pws) {

  __shared__ __align__(16) uint8_t lds[2 * KBUF];

  const int lane = threadIdx.x;       // 0..63
  const int c    = lane & 15;
  const int q    = lane >> 4;
  const int n0   = blockIdx.x * 32;
  const int kz   = blockIdx.y;        // K-quarter

  f32x4 acc[8][2] = {};               // [m-tile][even/odd col frag]

  // W staging: 4 lanes per k-row line; lane covers row rr=lane>>2 (+16m),
  // cols (lane&3)*8 .. +7 (32B fp32 = 2 float4, contiguous per lane).
  const int rr = lane >> 2, q4 = lane & 3;
  const float* wBase = w + (size_t)(kz * 1024 + rr) * NCOL + n0 + q4 * 8;
  const int ldsWOff = rr * WSTRIDE + q4 * 16;

  // A source (bf16 masked x, L2-resident): uint4 idx =
  //   (mt*16 + c)*512 + kz*128 + kbl*8 + ks*4 + q
  const uint4v* aBase = (const uint4v*)xbf + (size_t)c * 512 + kz * 128 + q;

  float4v wrA[8], wrB[8];             // two static prefetch register sets

#define LOAD_WR(WR, KBL)                                                   \
  {                                                                        \
    const float* wp = wBase + (size_t)(KBL) * 64 * NCOL;                   \
    _Pragma("unroll")                                                      \
    for (int m = 0; m < 4; ++m) {                                          \
      WR[m * 2 + 0] = *(const float4v*)(wp + (size_t)m * 16 * NCOL);       \
      WR[m * 2 + 1] = *(const float4v*)(wp + (size_t)m * 16 * NCOL + 4);   \
    }                                                                      \
  }

  // BODY: (1) A loads first (consuming them later never drains W prefetch —
  // vmcnt is in-order), (2) pack old WR -> LDS (waits only those 8 loads),
  // (3) reissue WR two kbs ahead, (4) ds_read + MFMA.
#define BODY(KBL, WR, BUF)                                                 \
  {                                                                        \
    union { uint4v u; short8 v; } am[2][8];                                \
    _Pragma("unroll")                                                      \
    for (int ks = 0; ks < 2; ++ks)                                         \
      _Pragma("unroll")                                                    \
      for (int mt = 0; mt < 8; ++mt)                                       \
        am[ks][mt].u = aBase[(size_t)mt * 16 * 512 + (KBL) * 8 + ks * 4];  \
    _Pragma("unroll")                                                      \
    for (int m = 0; m < 4; ++m) {                                          \
      uint4v v;                                                            \
      v[0] = pk_bf16(WR[m * 2 + 0][0], WR[m * 2 + 0][1]);                  \
      v[1] = pk_bf16(WR[m * 2 + 0][2], WR[m * 2 + 0][3]);                  \
      v[2] = pk_bf16(WR[m * 2 + 1][0], WR[m * 2 + 1][1]);                  \
      v[3] = pk_bf16(WR[m * 2 + 1][2], WR[m * 2 + 1][3]);                  \
      *(uint4v*)((BUF) + (size_t)m * 16 * WSTRIDE + ldsWOff) = v;          \
    }                                                                      \
    if ((KBL) < 14) LOAD_WR(WR, (KBL) + 2);                                \
    _Pragma("unroll")                                                      \
    for (int ks = 0; ks < 2; ++ks) {                                       \
      const uint8_t* wb = (BUF) + (size_t)(ks * 32 + q * 8) * WSTRIDE + c * 4; \
      unsigned wj[8];                                                      \
      _Pragma("unroll")                                                    \
      for (int j = 0; j < 8; ++j)                                          \
        wj[j] = *(const unsigned*)(wb + (size_t)j * WSTRIDE);              \
      union { short8 v; unsigned u[4]; } be, bo;                           \
      _Pragma("unroll")                                                    \
      for (int p = 0; p < 4; ++p) {                                        \
        be.u[p] = (wj[2 * p] & 0x0000ffffu) | (wj[2 * p + 1] << 16);       \
        bo.u[p] = (wj[2 * p] >> 16) | (wj[2 * p + 1] & 0xffff0000u);       \
      }                                                                    \
      _Pragma("unroll")                                                    \
      for (int mt = 0; mt < 8; ++mt) {                                     \
        acc[mt][0] = __builtin_amdgcn_mfma_f32_16x16x32_bf16(am[ks][mt].v, be.v, acc[mt][0], 0, 0, 0); \
        acc[mt][1] = __builtin_amdgcn_mfma_f32_16x16x32_bf16(am[ks][mt].v, bo.v, acc[mt][1], 0, 0, 0); \
      }                                                                    \
    }                                                                      \
  }

  LOAD_WR(wrA, 0);
  LOAD_WR(wrB, 1);
  for (int kbl = 0; kbl < 16; kbl += 2) {
    BODY(kbl,     wrA, lds);
    BODY(kbl + 1, wrB, lds + KBUF);
  }
#undef BODY
#undef LOAD_WR

  // epilogue: partial tile [128][32] fp32 to ws at [ntile][kz]
  float* P = pws + ((size_t)blockIdx.x * 4 + kz) * (128 * 32);
#pragma unroll
  for (int mt = 0; mt < 8; ++mt) {
#pragma unroll
    for (int p = 0; p < 4; ++p) {
      const int row = mt * 16 + q * 4 + p;
      float2v st;
      st[0] = acc[mt][0][p];
      st[1] = acc[mt][1][p];
      *(float2v*)(P + (size_t)row * 32 + 2 * c) = st;   // q-group = full 128B line
    }
  }
}

// ---- kernel 3: reduce 4 kz-partials + bias -> out. grid 2752 x 256.
__global__ __launch_bounds__(256) void reduce_kernel(
    const float* __restrict__ pws, const float* __restrict__ bias,
    float* __restrict__ out) {
  const int idx = blockIdx.x * 256 + threadIdx.x;   // 704512 float2's
  const int c2  = idx & 15;
  const int r   = (idx >> 4) & 127;
  const int nt  = idx >> 11;
  const float* p = pws + (size_t)nt * 4 * (128 * 32) + (size_t)r * 32 + c2 * 2;
  float2v s0 = *(const float2v*)(p);
  float2v s1 = *(const float2v*)(p + 128 * 32);
  float2v s2 = *(const float2v*)(p + 2 * 128 * 32);
  float2v s3 = *(const float2v*)(p + 3 * 128 * 32);
  const int col = nt * 32 + c2 * 2;
  float2v o;
  o[0] = s0[0] + s1[0] + s2[0] + s3[0] + bias[col];
  o[1] = s0[1] + s1[1] + s2[1] + s3[1] + bias[col + 1];
  *(float2v*)(out + (size_t)r * NCOL + col) = o;
}

extern "C" void kernel_launch(void* const* d_in, const int* in_sizes, int n_in,
                              void* d_out, int out_size, void* d_ws, size_t ws_size,
                              hipStream_t stream) {
  const float* x    = (const float*)d_in[0];
  const float* w    = (const float*)d_in[1];
  const float* bias = (const float*)d_in[2];
  float* out        = (float*)d_out;
  unsigned* xbf     = (unsigned*)d_ws;                       // 1 MiB bf16 x
  float* pws        = (float*)((char*)d_ws + (1u << 20));    // 22.5 MiB partials

  hipLaunchKernelGGL(mask_convert_kernel, dim3(8, 8), dim3(256), 0, stream, x, xbf);
  hipLaunchKernelGGL(gemm_kernel, dim3(344, 4), dim3(64), 0, stream, xbf, w, pws);
  hipLaunchKernelGGL(reduce_kernel, dim3(2752), dim3(256), 0, stream, pws, bias, out);
}

// Round 14
// 295.993 us; speedup vs baseline: 1.1856x; 1.0059x over previous
//
#include <hip/hip_runtime.h>
#include <stdint.h>

using f32x4   = __attribute__((ext_vector_type(4))) float;
using short8  = __attribute__((ext_vector_type(8))) short;
using float4v = __attribute__((ext_vector_type(4))) float;
using float2v = __attribute__((ext_vector_type(2))) float;
using uint4v  = __attribute__((ext_vector_type(4))) unsigned int;

#define NCOL 11008
#define KDIM 4096
#define LSTR 136            // LDS bytes per k-row: 64 cols * 2B + 8B pad

__device__ __forceinline__ unsigned pk_bf16(float a, float b) {
  unsigned ua = __float_as_uint(a); ua += 0x7fffu + ((ua >> 16) & 1u);  // RNE
  unsigned ub = __float_as_uint(b); ub += 0x7fffu + ((ub >> 16) & 1u);
  return (ua >> 16) | (ub & 0xffff0000u);
}

// ---- kernel 1: mask (fp64-exact; verified green R5–R13) + write mask-zeroed
//      bf16 copy of x into ws. grid (8 rb, 8 kgrp), 256 thr.
__global__ __launch_bounds__(256) void mask_convert_kernel(
    const float* __restrict__ x, unsigned* __restrict__ xbf) {
  const int rb = blockIdx.x;
  const int g  = blockIdx.y;
  const int t  = threadIdx.x;
  __shared__ double part[256];
  __shared__ unsigned sh_bits;

  const float* base = x + (size_t)rb * 16 * KDIM + g * 512 + t * 2;
  double s = 0.0;
#pragma unroll
  for (int r = 0; r < 16; ++r) {
    float2v a = *(const float2v*)(base + (size_t)r * KDIM);
    s += (double)fabsf(a[0]) + (double)fabsf(a[1]);
  }
  part[t] = s;
  __syncthreads();
  if (t < 8) {                        // t = kb-local (8 kbs per 512-col group)
    double acc = 0.0;
#pragma unroll
    for (int u = 0; u < 32; ++u) acc += part[t * 32 + u];
    bool on = (acc * (1.0 / 1024.0)) > (double)0.8f;
    unsigned long long bal = __ballot(on);
    if (t == 0) sh_bits = (unsigned)(bal & 0xffu);
  }
  __syncthreads();
  const unsigned keep = (sh_bits >> (t >> 5)) & 1u;

  unsigned* dst = xbf + (size_t)rb * 16 * (KDIM / 2) + g * 256 + t;
#pragma unroll
  for (int r = 0; r < 16; ++r) {      // reload (L1-hot) + pack/zero + store
    float2v a = *(const float2v*)(base + (size_t)r * KDIM);
    dst[(size_t)r * (KDIM / 2)] = keep ? pk_bf16(a[0], a[1]) : 0u;
  }
}

// ---- kernel 2: dense GEMM on masked bf16 x. grid (172 n-tiles, 8 kz),
// block 256 (4 waves as 2x2: wm = m-half, wn = col-32-half).
// M=128 x N=64 x K=512 per block -> 1376 blocks = 5.4/CU, 21.5 waves/CU:
// the barrier-drain of one block overlaps other blocks' bursts (m114).
// Every W byte read by exactly one block; partials to ws (no atomics).
__global__ __launch_bounds__(256) void gemm_kernel(
    const unsigned* __restrict__ xbf, const float* __restrict__ w,
    float* __restrict__ pws) {

  __shared__ __align__(16) uint8_t lds[64 * LSTR];   // 8.5 KB bf16 W tile

  const int tid  = threadIdx.x;
  const int lane = tid & 63;
  const int wv   = tid >> 6;
  const int wm   = wv >> 1;           // m-half: rows wm*64 .. +63
  const int wn   = wv & 1;            // col-half: cols wn*32 .. +31
  const int c    = lane & 15;
  const int q    = lane >> 4;
  const int n0   = blockIdx.x * 64;
  const int kz   = blockIdx.y;        // K-slice [kz*512, +512)

  f32x4 acc[4][2] = {};               // [mt][even/odd]

  // W staging: thread t -> k-row r = t>>2 (0..63), col-group g4 = t&3 (16 cols)
  // global: 64B contiguous per thread, 4 threads cover a 256B row chunk.
  const int sr = tid >> 2, g4 = tid & 3;
  const float* wBase = w + (size_t)(kz * 512 + sr) * NCOL + n0 + g4 * 16;
  uint8_t* wS = lds + (size_t)sr * LSTR + g4 * 32;

  float4v wr0, wr1, wr2, wr3;         // static names: no runtime-indexed array
#define ISSUE_W(KB)                                                     \
  {                                                                     \
    const float* wp = wBase + (size_t)(KB) * 64 * NCOL;                 \
    wr0 = *(const float4v*)(wp);                                        \
    wr1 = *(const float4v*)(wp + 4);                                    \
    wr2 = *(const float4v*)(wp + 8);                                    \
    wr3 = *(const float4v*)(wp + 12);                                   \
  }

  // A source (bf16 masked x, L2-resident):
  // uint4 idx = row*512 + kz*64 + kb*8 + ks*4 + q, row = wm*64 + mt*16 + c
  const uint4v* aBase = (const uint4v*)xbf +
                        ((size_t)(wm * 64 + c)) * (KDIM / 8) + kz * 64 + q;

  ISSUE_W(0);
  for (int kb = 0; kb < 8; ++kb) {
    __syncthreads();                  // prior compute done reading LDS
    {                                 // pack W(kb) fp32->bf16, store
      uint4v v;
      v[0] = pk_bf16(wr0[0], wr0[1]);
      v[1] = pk_bf16(wr0[2], wr0[3]);
      v[2] = pk_bf16(wr1[0], wr1[1]);
      v[3] = pk_bf16(wr1[2], wr1[3]);
      *(uint4v*)(wS) = v;
      uint4v u;
      u[0] = pk_bf16(wr2[0], wr2[1]);
      u[1] = pk_bf16(wr2[2], wr2[3]);
      u[2] = pk_bf16(wr3[0], wr3[1]);
      u[3] = pk_bf16(wr3[2], wr3[3]);
      *(uint4v*)(wS + 16) = u;
    }
    __syncthreads();
    if (kb < 7) ISSUE_W(kb + 1);      // issued before compute; barrier pins order

#pragma unroll
    for (int ks = 0; ks < 2; ++ks) {
      union { uint4v u; short8 v; } am[4];
#pragma unroll
      for (int mt = 0; mt < 4; ++mt)
        am[mt].u = aBase[(size_t)mt * 16 * (KDIM / 8) + kb * 8 + ks * 4];

      // B fragments: dword j = cols (2c,2c+1) at k = ks*32 + q*8 + j
      const uint8_t* wb = lds + (size_t)(ks * 32 + q * 8) * LSTR + (wn * 32 + 2 * c) * 2;
      unsigned wj[8];
#pragma unroll
      for (int j = 0; j < 8; ++j)
        wj[j] = *(const unsigned*)(wb + (size_t)j * LSTR);
      union { short8 v; unsigned u[4]; } be, bo;
#pragma unroll
      for (int p = 0; p < 4; ++p) {
        be.u[p] = (wj[2 * p] & 0x0000ffffu) | (wj[2 * p + 1] << 16);   // even col
        bo.u[p] = (wj[2 * p] >> 16) | (wj[2 * p + 1] & 0xffff0000u);   // odd col
      }
#pragma unroll
      for (int mt = 0; mt < 4; ++mt) {
        acc[mt][0] = __builtin_amdgcn_mfma_f32_16x16x32_bf16(am[mt].v, be.v, acc[mt][0], 0, 0, 0);
        acc[mt][1] = __builtin_amdgcn_mfma_f32_16x16x32_bf16(am[mt].v, bo.v, acc[mt][1], 0, 0, 0);
      }
    }
  }
#undef ISSUE_W

  // epilogue: partial tile [128][64] fp32 at pws[(nt*8+kz)*8192]
  float* P = pws + ((size_t)blockIdx.x * 8 + kz) * (128 * 64);
  const int colL = wn * 32 + 2 * c;
#pragma unroll
  for (int mt = 0; mt < 4; ++mt) {
#pragma unroll
    for (int p = 0; p < 4; ++p) {
      const int row = wm * 64 + mt * 16 + q * 4 + p;
      float2v st;
      st[0] = acc[mt][0][p];
      st[1] = acc[mt][1][p];
      *(float2v*)(P + (size_t)row * 64 + colL) = st;
    }
  }
}

// ---- kernel 3: reduce 8 kz-partials + bias -> out. grid 2752 x 256.
__global__ __launch_bounds__(256) void reduce_kernel(
    const float* __restrict__ pws, const float* __restrict__ bias,
    float* __restrict__ out) {
  const int idx = blockIdx.x * 256 + threadIdx.x;   // 172*128*32 = 704512 float2
  const int c2  = idx & 31;
  const int r   = (idx >> 5) & 127;
  const int nt  = idx >> 12;
  const float* p = pws + (size_t)nt * 8 * (128 * 64) + (size_t)r * 64 + c2 * 2;
  float s0 = 0.f, s1 = 0.f;
#pragma unroll
  for (int z = 0; z < 8; ++z) {
    float2v v = *(const float2v*)(p + (size_t)z * (128 * 64));
    s0 += v[0]; s1 += v[1];
  }
  const int col = nt * 64 + c2 * 2;
  float2v o;
  o[0] = s0 + bias[col];
  o[1] = s1 + bias[col + 1];
  *(float2v*)(out + (size_t)r * NCOL + col) = o;
}

extern "C" void kernel_launch(void* const* d_in, const int* in_sizes, int n_in,
                              void* d_out, int out_size, void* d_ws, size_t ws_size,
                              hipStream_t stream) {
  const float* x    = (const float*)d_in[0];
  const float* w    = (const float*)d_in[1];
  const float* bias = (const float*)d_in[2];
  float* out        = (float*)d_out;
  unsigned* xbf     = (unsigned*)d_ws;                       // 1 MiB bf16 x
  float* pws        = (float*)((char*)d_ws + (1u << 20));    // 45 MiB partials

  hipLaunchKernelGGL(mask_convert_kernel, dim3(8, 8), dim3(256), 0, stream, x, xbf);
  hipLaunchKernelGGL(gemm_kernel, dim3(172, 8), dim3(256), 0, stream, xbf, w, pws);
  hipLaunchKernelGGL(reduce_kernel, dim3(2752), dim3(256), 0, stream, pws, bias, out);
}